// Round 5
// baseline (85.453 us; speedup 1.0000x reference)
//
#include <hip/hip_runtime.h>
#include <hip/hip_bf16.h>

// MaxPoolingMatching: out[b,l,p] = max_m cos( s1[b,l,:]∘k[p,:], s2[b,m,:]∘k[p,:] )
// B=16, L=256, D=256, P=20.
//
// v5: A-operand (bf16(s2), p-INDEPENDENT) lives in 128 VGPRs per wave, loaded once
// from global (L2-resident 2MB) — X2 LDS staging and its reads are gone. LDS carries
// only X1 = bf16(s1·k²·rn1) (32 l-rows, 16KB, XOR-swizzled), rebuilt per p from a
// bf16(s1) register cache. Wave tile 64m×32l (4×2 of 16x16x32 MFMA); block = 4 waves
// = 256m × 32l; grid 512 = b(16)×lt(8)×pgi(4) → 2 blocks/CU, 2 waves/SIMD.
// K-loop: 2 ds_read_b128 + 8 MFMA per kstep. prep2 (MFMA-based norms) unchanged.

#define B_DIM 16
#define L_DIM 256
#define D_DIM 256
#define P_DIM 20
#define EPS 1e-12f
#define LDP 264   // prep2 padded stride

typedef __attribute__((ext_vector_type(8))) __bf16 bf16x8;
typedef __attribute__((ext_vector_type(4))) float f32x4;

__device__ __forceinline__ unsigned short f2bf(float x) {
  unsigned int u = __float_as_uint(x);
  u += 0x7fffu + ((u >> 16) & 1u);   // RNE
  return (unsigned short)(u >> 16);
}

// ---------------- prep2: MFMA norms + bf16 casts (validated in v4) ----------------
__global__ __launch_bounds__(256)
void prep2(const float* __restrict__ s1, const float* __restrict__ s2,
           const float* __restrict__ kg,
           float* __restrict__ rn1, float* __restrict__ rn2,
           unsigned short* __restrict__ s1bf, unsigned short* __restrict__ s2bf) {
  __shared__ __align__(16) unsigned short QA[32 * LDP];
  __shared__ __align__(16) unsigned short QB[32 * LDP];
  const int tid = threadIdx.x, lane = tid & 63, wave = tid >> 6;
  const int lr = lane & 15, q = lane >> 4;
  const int sent = blockIdx.x & 1, t = blockIdx.x >> 1;
  const int r0 = t * 32, b = r0 >> 8;
  const float* src = sent ? s2 : s1;
  unsigned short* sbf = sent ? s2bf : s1bf;
  float* rn = sent ? rn2 : rn1;

  #pragma unroll
  for (int i = 0; i < 8; ++i) {
    const int row = i * 4 + wave;
    float4 sv = *(const float4*)(src + (size_t)(r0 + row) * D_DIM + lane * 4);
    unsigned int c0 = ((unsigned int)f2bf(sv.y) << 16) | f2bf(sv.x);
    unsigned int c1 = ((unsigned int)f2bf(sv.w) << 16) | f2bf(sv.z);
    *(uint2*)&sbf[(size_t)(r0 + row) * D_DIM + lane * 4] = make_uint2(c0, c1);
    unsigned int q0 = ((unsigned int)f2bf(sv.y * sv.y) << 16) | f2bf(sv.x * sv.x);
    unsigned int q1 = ((unsigned int)f2bf(sv.w * sv.w) << 16) | f2bf(sv.z * sv.z);
    *(uint2*)&QA[row * LDP + lane * 4] = make_uint2(q0, q1);
  }
  #pragma unroll
  for (int j = 0; j < 5; ++j) {
    const int row = wave * 5 + j;   // 0..19; rows 20..31 garbage (masked at write)
    float4 kv = *(const float4*)(kg + row * D_DIM + lane * 4);
    unsigned int c0 = ((unsigned int)f2bf(kv.y * kv.y) << 16) | f2bf(kv.x * kv.x);
    unsigned int c1 = ((unsigned int)f2bf(kv.w * kv.w) << 16) | f2bf(kv.z * kv.z);
    *(uint2*)&QB[row * LDP + lane * 4] = make_uint2(c0, c1);
  }
  __syncthreads();

  const int mt = wave & 1, nt = wave >> 1;
  f32x4 acc = {0.f, 0.f, 0.f, 0.f};
  #pragma unroll
  for (int ks = 0; ks < 8; ++ks) {
    const int cc = ks * 4 + q;
    bf16x8 a  = *(const bf16x8*)&QA[(mt * 16 + lr) * LDP + cc * 8];
    bf16x8 bb = *(const bf16x8*)&QB[(nt * 16 + lr) * LDP + cc * 8];
    acc = __builtin_amdgcn_mfma_f32_16x16x32_bf16(a, bb, acc, 0, 0, 0);
  }
  const int p = nt * 16 + lr;
  if (p < P_DIM) {
    #pragma unroll
    for (int r = 0; r < 4; ++r) {
      const int l = (r0 & 255) + mt * 16 + q * 4 + r;
      rn[((size_t)b * P_DIM + p) * L_DIM + l] = rsqrtf(fmaxf(acc[r], EPS));
    }
  }
}

// ---------------- main ----------------
__global__ __launch_bounds__(256, 2)
void mpm_main(const unsigned short* __restrict__ s1bf,
              const unsigned short* __restrict__ s2bf,
              const float* __restrict__ kg, const float* __restrict__ rn1,
              const float* __restrict__ rn2, float* __restrict__ outg) {
  __shared__ __align__(16) unsigned short X1[32 * 256];   // 16KB, 32 l rows, swizzled
  __shared__ float Wout[4 * 32];                          // per-wave l-maxes

  const int tid = threadIdx.x, lane = tid & 63, wave = tid >> 6;  // 4 waves
  const int lr = lane & 15, q = lane >> 4;
  const int bid = blockIdx.x;      // 512 = b(16) x lt(8) x pgi(4)
  const int pgi = bid & 3, lt = (bid >> 2) & 7, b = bid >> 5;
  const int l0 = lt * 32;

  // ---- A-operand in registers: wave's 64 m-rows × K=256 bf16 = 128 VGPRs ----
  // 16x16x32 A-layout: lane holds row m = mi*16 + lr, k = ks*32 + q*8 + {0..7}
  bf16x8 areg[4][8];
  {
    const unsigned short* s2b = s2bf + (size_t)b * L_DIM * D_DIM;
    #pragma unroll
    for (int mi = 0; mi < 4; ++mi) {
      const unsigned short* rp = s2b + (size_t)(wave * 64 + mi * 16 + lr) * D_DIM + q * 8;
      #pragma unroll
      for (int ks = 0; ks < 8; ++ks)
        areg[mi][ks] = *(const bf16x8*)(rp + ks * 32);
    }
  }

  // ---- bf16(s1) register cache: 8 rows/wave, 8B/lane ----
  uint2 s1r[8];
  {
    const unsigned short* s1b = s1bf + ((size_t)b * L_DIM + l0) * D_DIM;
    #pragma unroll
    for (int i = 0; i < 8; ++i)
      s1r[i] = *(const uint2*)(s1b + (size_t)(i * 4 + wave) * D_DIM + lane * 4);
  }

  #pragma unroll 1
  for (int pp = 0; pp < 5; ++pp) {
    const int p = pgi * 5 + pp;

    // build X1 = bf16( s1 * k^2 * rn1 ), swizzled 8B stores (rows 0..31, key=row)
    {
      float4 kv = *(const float4*)(kg + p * D_DIM + lane * 4);
      const float k0 = kv.x * kv.x, k1 = kv.y * kv.y, k2 = kv.z * kv.z, k3 = kv.w * kv.w;
      const float* rn1b = rn1 + ((size_t)b * P_DIM + p) * L_DIM + l0;
      #pragma unroll
      for (int i = 0; i < 8; ++i) {
        const int row = i * 4 + wave;
        const float rv = rn1b[row];                       // wave-uniform
        float x0 = __uint_as_float(s1r[i].x << 16)         * k0 * rv;
        float x1 = __uint_as_float(s1r[i].x & 0xffff0000u) * k1 * rv;
        float x2 = __uint_as_float(s1r[i].y << 16)         * k2 * rv;
        float x3 = __uint_as_float(s1r[i].y & 0xffff0000u) * k3 * rv;
        unsigned int c0 = ((unsigned int)f2bf(x1) << 16) | f2bf(x0);
        unsigned int c1 = ((unsigned int)f2bf(x3) << 16) | f2bf(x2);
        *(uint2*)&X1[row * 256 + (((lane >> 1) ^ row) << 3) + ((lane & 1) << 2)] =
            make_uint2(c0, c1);
      }
    }
    __syncthreads();   // X1 visible (also: prior p's Wout reads complete)

    // ---- K-loop: wave computes C[64m x 32l]; A from VGPRs, B from LDS ----
    f32x4 acc[4][2];
    #pragma unroll
    for (int mi = 0; mi < 4; ++mi) {
      acc[mi][0] = (f32x4){0.f, 0.f, 0.f, 0.f};
      acc[mi][1] = (f32x4){0.f, 0.f, 0.f, 0.f};
    }
    #pragma unroll
    for (int ks = 0; ks < 8; ++ks) {
      const int cc = ks * 4 + q;
      bf16x8 b0 = *(const bf16x8*)&X1[(lr)      * 256 + ((cc ^ lr) << 3)];
      bf16x8 b1 = *(const bf16x8*)&X1[(16 + lr) * 256 + ((cc ^ (16 + lr)) << 3)];
      #pragma unroll
      for (int mi = 0; mi < 4; ++mi) {
        acc[mi][0] = __builtin_amdgcn_mfma_f32_16x16x32_bf16(areg[mi][ks], b0, acc[mi][0], 0, 0, 0);
        acc[mi][1] = __builtin_amdgcn_mfma_f32_16x16x32_bf16(areg[mi][ks], b1, acc[mi][1], 0, 0, 0);
      }
    }

    // ---- epilogue: C row = m = wave*64 + mi*16 + q*4 + r ; col l = li*16 + lr ----
    float4 r2[4];
    {
      const float* rn2b = rn2 + ((size_t)b * P_DIM + p) * L_DIM + wave * 64;
      #pragma unroll
      for (int mi = 0; mi < 4; ++mi)
        r2[mi] = *(const float4*)(rn2b + mi * 16 + q * 4);
    }
    float v[2];
    #pragma unroll
    for (int li = 0; li < 2; ++li) {
      float t = -3.4e38f;
      #pragma unroll
      for (int mi = 0; mi < 4; ++mi) {
        t = fmaxf(t, acc[mi][li][0] * r2[mi].x);
        t = fmaxf(t, acc[mi][li][1] * r2[mi].y);
        t = fmaxf(t, acc[mi][li][2] * r2[mi].z);
        t = fmaxf(t, acc[mi][li][3] * r2[mi].w);
      }
      t = fmaxf(t, __shfl_xor(t, 16));
      t = fmaxf(t, __shfl_xor(t, 32));
      v[li] = t;
    }
    if (q == 0) {
      Wout[wave * 32 + lr]      = v[0];
      Wout[wave * 32 + 16 + lr] = v[1];
    }
    __syncthreads();   // Wout visible; X1 reads done -> next build may overwrite
    if (tid < 32) {
      float o = fmaxf(fmaxf(Wout[tid], Wout[32 + tid]),
                      fmaxf(Wout[64 + tid], Wout[96 + tid]));
      outg[((size_t)b * L_DIM + (l0 + tid)) * P_DIM + p] = o;
    }
  }
}

extern "C" void kernel_launch(void* const* d_in, const int* in_sizes, int n_in,
                              void* d_out, int out_size, void* d_ws, size_t ws_size,
                              hipStream_t stream) {
  const float* s1 = (const float*)d_in[0];
  const float* s2 = (const float*)d_in[1];
  const float* kg = (const float*)d_in[2];
  float* out = (float*)d_out;

  // ws: rn1 | rn2 (B*P*L f32 each) | s2bf | s1bf (B*L*D bf16 each)  ≈ 9 MB
  float* rn1 = (float*)d_ws;
  float* rn2 = rn1 + (size_t)B_DIM * P_DIM * L_DIM;
  unsigned short* s2bf = (unsigned short*)(rn2 + (size_t)B_DIM * P_DIM * L_DIM);
  unsigned short* s1bf = s2bf + (size_t)B_DIM * L_DIM * D_DIM;

  prep2<<<dim3(256), dim3(256), 0, stream>>>(s1, s2, kg, rn1, rn2, s1bf, s2bf);
  mpm_main<<<dim3(512), dim3(256), 0, stream>>>(s1bf, s2bf, kg, rn1, rn2, out);
}